// Round 12
// baseline (209.587 us; speedup 1.0000x reference)
//
#include <hip/hip_runtime.h>

typedef short v8s __attribute__((ext_vector_type(8)));
typedef float v4f __attribute__((ext_vector_type(4)));
typedef unsigned v4u __attribute__((ext_vector_type(4)));

#define Wh   1024
#define Hh   512
#define HWh  (Wh * Hh)
#define Wlr  512
#define HWlr (Wlr * 256)
#define ITERS 8
#define NBLK  512         // 512 blocks x 8 waves x 8 iters x 16 px = 524288 px (1 row/block)

// LDS layout (shorts): wfrag[53*512] only (act buffer eliminated — register relay)
#define WFRAG_SHORTS (53 * 512)
#define LDS_BYTES    (WFRAG_SHORTS * 2)   // 54272

__device__ __forceinline__ unsigned short f2bf(float f) {
    union { float f; unsigned u; } v; v.f = f;
    unsigned r = v.u + 0x7FFFu + ((v.u >> 16) & 1u);  // RNE (cold paths only)
    return (unsigned short)(r >> 16);
}
// hot-path pack: single-instruction packed f32->bf16 (RNE; dst.lo=a, dst.hi=b)
__device__ __forceinline__ unsigned pk2(float a, float b) {
    unsigned r;
    asm("v_cvt_pk_bf16_f32 %0, %1, %2" : "=v"(r) : "v"(a), "v"(b));
    return r;
}
__device__ __forceinline__ float leaky(float x) { return fmaxf(x, 0.01f * x); }

// register relay: build next layer's B-fragment (K-slot ks*32+q*8+j) from this
// layer's two accumulators for mt=2ks ("e") and mt=2ks+1 ("o").
// K-permuted weights ensure slot (ks,j) <- channel (2ks+(j>>2))*16 + q*4 + (j&3).
__device__ __forceinline__ v8s relay(v4f e, v4f o) {
    v4u w;
    w[0] = pk2(leaky(e[0]), leaky(e[1]));
    w[1] = pk2(leaky(e[2]), leaky(e[3]));
    w[2] = pk2(leaky(o[0]), leaky(o[1]));
    w[3] = pk2(leaky(o[2]), leaky(o[3]));
    return __builtin_bit_cast(v8s, w);
}

// 512-thread blocks, min 4 waves/EU -> VGPR cap 128 (the granule boundary:
// 65..128 VGPR all give 4 waves/SIMD — m69). Live set estimate ~120 with the
// L1-fragment hoist; cap 128 > live, so no spill expected (unlike R4's cap 85
// < live ~100 which spilled). Tripwire: WRITE_SIZE > 5MB => spilled, revert.
__global__ __launch_bounds__(512, 4)
void cmfsm_kernel(const float* __restrict__ lr, const float* __restrict__ hr,
                  const float* __restrict__ w0g, const float* __restrict__ w1g,
                  const float* __restrict__ w2g, const float* __restrict__ w3g,
                  const float* __restrict__ w4g, const float* __restrict__ w5g,
                  const float* __restrict__ t0g, const float* __restrict__ t1g,
                  const float* __restrict__ t2g, const float* __restrict__ fwg,
                  float* __restrict__ out)
{
    extern __shared__ unsigned short smem[];
    unsigned short* wfrag = smem;                    // 53*512 shorts

    const int tid  = threadIdx.x;
    const int lane = tid & 63;
    const int wv   = tid >> 6;    // 0..7
    const int p    = lane & 15;   // MFMA n (pixel)
    const int q    = lane >> 4;   // MFMA k-quad

    // ---- stage weights as A-fragments into LDS, fragment-major ----
    // layer 0: identity K mapping (B built straight from global loads)
    for (int e = tid; e < 32 * 64; e += 512) {
        int f = e >> 6, l = e & 63;
        int mt = f >> 2, ks = f & 3, pp = l & 15, qq = l >> 4;
        const float* src = w0g + (mt * 16 + pp) * 128 + ks * 32 + qq * 8;
        unsigned short* dst = wfrag + f * 512 + l * 8;
#pragma unroll
        for (int j = 0; j < 8; ++j) dst[j] = f2bf(src[j]);
    }
    // layers 1..3: K-permuted so B comes from the register relay.
    // slot (ks, qq, j) <- input channel ks*32 + ((j>>2)<<4) + qq*4 + (j&3)
    for (int e = tid; e < 16 * 64; e += 512) {
        int f = e >> 6, l = e & 63;
        int mt = f >> 2, ks = f & 3, pp = l & 15, qq = l >> 4;
        const float* srcrow = w1g + (mt * 16 + pp) * 128;
        unsigned short* dst = wfrag + (32 + f) * 512 + l * 8;
#pragma unroll
        for (int j = 0; j < 8; ++j)
            dst[j] = f2bf(srcrow[ks * 32 + ((j >> 2) << 4) + qq * 4 + (j & 3)]);
    }
    if (tid < 4 * 64) {
        int f = tid >> 6, l = tid & 63;
        int mt = f >> 1, ks = f & 1, pp = l & 15, qq = l >> 4;
        const float* srcrow = w2g + (mt * 16 + pp) * 64;
        unsigned short* dst = wfrag + (48 + f) * 512 + l * 8;
#pragma unroll
        for (int j = 0; j < 8; ++j)
            dst[j] = f2bf(srcrow[ks * 32 + ((j >> 2) << 4) + qq * 4 + (j & 3)]);
    }
    if (tid < 64) {
        int l = tid;
        int pp = l & 15, qq = l >> 4;
        const float* srcrow = w3g + pp * 32;
        unsigned short* dst = wfrag + 52 * 512 + l * 8;
#pragma unroll
        for (int j = 0; j < 8; ++j)
            dst[j] = f2bf(srcrow[((j >> 2) << 4) + qq * 4 + (j & 3)]);
    }

    // ---- fused linear layers 4+5: w45[r] = sum_j w5[j]*w4[j][4q+r] ----
    float w45[4];
#pragma unroll
    for (int r = 0; r < 4; ++r) {
        float s = 0.f;
#pragma unroll
        for (int j = 0; j < 8; ++j) s += w5g[j] * w4g[j * 16 + q * 4 + r];
        w45[r] = s;
    }

    // ---- weights2: 4 parity values; row parity is block-uniform (y = blockIdx) ----
    float w2e, w2o;   // value for even-x / odd-x pixels of this row
    {
        float tab[4];
#pragma unroll
        for (int yp = 0; yp < 2; ++yp)
#pragma unroll
            for (int xp = 0; xp < 2; ++xp) {
                float i0 = xp ? 1.f : -1.f;
                float i1 = yp ? 1.f : -1.f;
                float i2 = 1.41421356237309505f;
                float h0[3], h1[2];
                for (int o = 0; o < 3; ++o)
                    h0[o] = leaky(t0g[o*3+0]*i0 + t0g[o*3+1]*i1 + t0g[o*3+2]*i2);
                for (int o = 0; o < 2; ++o)
                    h1[o] = leaky(t1g[o*3+0]*h0[0] + t1g[o*3+1]*h0[1] + t1g[o*3+2]*h0[2]);
                tab[yp*2+xp] = t2g[0]*h1[0] + t2g[1]*h1[1];
            }
        const int yp = blockIdx.x & 1;
        w2e = yp ? tab[2] : tab[0];
        w2o = yp ? tab[3] : tab[1];
    }
    const float fa = fabsf(fwg[0]);
    const float fb = fabsf(fwg[1]);

    __syncthreads();   // wfrag ready; everything after is wave-private

    const unsigned short* WL = wfrag + lane * 8;     // A-frag read base

    // ---- per-lane per-channel global pointers: lane (q,p) owns ch = q*8+j ----
    const float* hrp[8];
    const float* lrp[8];
    {
        const int hbase = blockIdx.x * Wh + wv * 16 + p;
        const int lbase = (blockIdx.x >> 1) * Wlr + wv * 8 + (p >> 1);
#pragma unroll
        for (int j = 0; j < 8; ++j) {
            hrp[j] = hr + (size_t)(q * 8 + j) * HWh  + hbase;
            lrp[j] = lr + (size_t)(q * 8 + j) * HWlr + lbase;
        }
    }

    // ---- hoist loop-invariant A-fragments to registers:
    //   L1: 16 frags (64 VGPR) — removes 16 of 48 ds_read_b128 per iter
    //   L2+L3: 5 frags (20 VGPR) — removes the serial-tail LDS reads (R6 win)
    v8s a1w[16];
#pragma unroll
    for (int i = 0; i < 16; ++i) a1w[i] = *(const v8s*)(WL + (32 + i) * 512);
    const v8s a2w[4] = {
        *(const v8s*)(WL + 48 * 512), *(const v8s*)(WL + 49 * 512),
        *(const v8s*)(WL + 50 * 512), *(const v8s*)(WL + 51 * 512)
    };
    const v8s a3 = *(const v8s*)(WL + 52 * 512);

    // persistent zero C-tuple: chains start as mfma(a,b,z4) — no per-chain movs
    const v4f z4 = (v4f){0.f, 0.f, 0.f, 0.f};

    // output column base for this wave (q==0 lanes store)
    const int obase = blockIdx.x * Wh + wv * 16 + p;

    // ---- software pipeline: preload iteration 0's staging values ----
    float h[8], l[8];
#pragma unroll
    for (int j = 0; j < 8; ++j) { h[j] = hrp[j][0]; l[j] = lrp[j][0]; }

#pragma unroll
    for (int it = 0; it < ITERS; ++it) {
        // ---- layer-0 B fragments in registers ----
        //   ks0 = lr_up, ks1 = hr, ks2 = lr*hr, ks3 = (lr-hr)^2
        v4u bf0, bf1, bf2, bf3;
#pragma unroll
        for (int u = 0; u < 4; ++u) {
            float l0 = l[2*u], l1 = l[2*u+1];
            float h0 = h[2*u], h1 = h[2*u+1];
            bf0[u] = pk2(l0, l1);
            bf1[u] = pk2(h0, h1);
            bf2[u] = pk2(l0 * h0, l1 * h1);
            float d0 = l0 - h0, d1 = l1 - h1;
            bf3[u] = pk2(d0 * d0, d1 * d1);
        }
        v8s b0 = __builtin_bit_cast(v8s, bf0);
        v8s b1 = __builtin_bit_cast(v8s, bf1);
        v8s b2 = __builtin_bit_cast(v8s, bf2);
        v8s b3 = __builtin_bit_cast(v8s, bf3);

        // ---- prefetch next iteration (all-immediate addressing, it static) ----
        if (it + 1 < ITERS) {
            const int ho = (it + 1) * 128;   // hr: +128 floats/iter (imm 512B steps)
            const int lo = (it + 1) * 64;    // lr: +64 floats/iter  (imm 256B steps)
#pragma unroll
            for (int j = 0; j < 8; ++j) {
                h[j] = hrp[j][ho];
                l[j] = lrp[j][lo];
            }
        }

        // ---- layer 0: 128 -> 128, pair-wise relay, zero-peeled chains ----
        v8s c1[4];
#pragma unroll
        for (int ksp = 0; ksp < 4; ++ksp) {
            v4f ae = __builtin_amdgcn_mfma_f32_16x16x32_bf16(
                         *(const v8s*)(WL + ((2 * ksp)     * 4) * 512), b0, z4, 0, 0, 0);
            v4f ao = __builtin_amdgcn_mfma_f32_16x16x32_bf16(
                         *(const v8s*)(WL + ((2 * ksp + 1) * 4) * 512), b0, z4, 0, 0, 0);
#pragma unroll
            for (int ks = 1; ks < 4; ++ks) {
                v8s b = (ks == 1) ? b1 : (ks == 2) ? b2 : b3;
                v8s we = *(const v8s*)(WL + ((2 * ksp)     * 4 + ks) * 512);
                v8s wo = *(const v8s*)(WL + ((2 * ksp + 1) * 4 + ks) * 512);
                ae = __builtin_amdgcn_mfma_f32_16x16x32_bf16(we, b, ae, 0, 0, 0);
                ao = __builtin_amdgcn_mfma_f32_16x16x32_bf16(wo, b, ao, 0, 0, 0);
            }
            c1[ksp] = relay(ae, ao);
        }

        // ---- layer 1: 128 -> 64, A-frags in registers, zero-peeled ----
        v8s c2[2];
#pragma unroll
        for (int ksp = 0; ksp < 2; ++ksp) {
            v4f ae = __builtin_amdgcn_mfma_f32_16x16x32_bf16(
                         a1w[(2 * ksp) * 4], c1[0], z4, 0, 0, 0);
            v4f ao = __builtin_amdgcn_mfma_f32_16x16x32_bf16(
                         a1w[(2 * ksp + 1) * 4], c1[0], z4, 0, 0, 0);
#pragma unroll
            for (int ks = 1; ks < 4; ++ks) {
                ae = __builtin_amdgcn_mfma_f32_16x16x32_bf16(
                         a1w[(2 * ksp) * 4 + ks],     c1[ks], ae, 0, 0, 0);
                ao = __builtin_amdgcn_mfma_f32_16x16x32_bf16(
                         a1w[(2 * ksp + 1) * 4 + ks], c1[ks], ao, 0, 0, 0);
            }
            c2[ksp] = relay(ae, ao);
        }

        // ---- layer 2: 64 -> 32 (single pair, A-frags in registers, zero-peeled) ----
        v8s c3;
        {
            v4f ae = __builtin_amdgcn_mfma_f32_16x16x32_bf16(a2w[0], c2[0], z4, 0, 0, 0);
            v4f ao = __builtin_amdgcn_mfma_f32_16x16x32_bf16(a2w[2], c2[0], z4, 0, 0, 0);
            ae = __builtin_amdgcn_mfma_f32_16x16x32_bf16(a2w[1], c2[1], ae, 0, 0, 0);
            ao = __builtin_amdgcn_mfma_f32_16x16x32_bf16(a2w[3], c2[1], ao, 0, 0, 0);
            c3 = relay(ae, ao);
        }

        // ---- layer 3: 32 -> 16, fused 16->8->1, fuse with weights2 ----
        {
            v4f acc3 = __builtin_amdgcn_mfma_f32_16x16x32_bf16(a3, c3, z4, 0, 0, 0);

            float part = 0.f;
#pragma unroll
            for (int r = 0; r < 4; ++r) part += w45[r] * leaky(acc3[r]);
            part += __shfl_xor(part, 16, 64);
            part += __shfl_xor(part, 32, 64);

            if (q == 0) {
                const float w2v = (p & 1) ? w2o : w2e;
                out[obase + it * 128] = fa * part + fb * w2v;
            }
        }
    }
}

extern "C" void kernel_launch(void* const* d_in, const int* in_sizes, int n_in,
                              void* d_out, int out_size, void* d_ws, size_t ws_size,
                              hipStream_t stream) {
    const float* lr  = (const float*)d_in[0];
    const float* hr  = (const float*)d_in[1];
    const float* w0g = (const float*)d_in[2];
    const float* w1g = (const float*)d_in[3];
    const float* w2g = (const float*)d_in[4];
    const float* w3g = (const float*)d_in[5];
    const float* w4g = (const float*)d_in[6];
    const float* w5g = (const float*)d_in[7];
    const float* t0g = (const float*)d_in[8];
    const float* t1g = (const float*)d_in[9];
    const float* t2g = (const float*)d_in[10];
    const float* fwg = (const float*)d_in[11];
    float* out = (float*)d_out;

    hipLaunchKernelGGL(cmfsm_kernel, dim3(NBLK), dim3(512), LDS_BYTES, stream,
                       lr, hr, w0g, w1g, w2g, w3g, w4g, w5g, t0g, t1g, t2g, fwg, out);
}

// Round 13
// 145.744 us; speedup vs baseline: 1.4380x; 1.4380x over previous
//
#include <hip/hip_runtime.h>

typedef short v8s __attribute__((ext_vector_type(8)));
typedef float v4f __attribute__((ext_vector_type(4)));
typedef unsigned v4u __attribute__((ext_vector_type(4)));

#define Wh   1024
#define Hh   512
#define HWh  (Wh * Hh)
#define Wlr  512
#define HWlr (Wlr * 256)
#define ITERS 8
#define NBLK  512         // 512 blocks x 8 waves x 8 iters x 16 px = 524288 px (1 row/block)

// LDS layout (shorts): wfrag[53*512] only (act buffer eliminated — register relay)
#define WFRAG_SHORTS (53 * 512)
#define LDS_BYTES    (WFRAG_SHORTS * 2)   // 54272

__device__ __forceinline__ unsigned short f2bf(float f) {
    union { float f; unsigned u; } v; v.f = f;
    unsigned r = v.u + 0x7FFFu + ((v.u >> 16) & 1u);  // RNE (cold paths only)
    return (unsigned short)(r >> 16);
}
// hot-path pack: single-instruction packed f32->bf16 (RNE; dst.lo=a, dst.hi=b)
__device__ __forceinline__ unsigned pk2(float a, float b) {
    unsigned r;
    asm("v_cvt_pk_bf16_f32 %0, %1, %2" : "=v"(r) : "v"(a), "v"(b));
    return r;
}
__device__ __forceinline__ float leaky(float x) { return fmaxf(x, 0.01f * x); }

// register relay: build next layer's B-fragment (K-slot ks*32+q*8+j) from this
// layer's two accumulators for mt=2ks ("e") and mt=2ks+1 ("o").
// K-permuted weights ensure slot (ks,j) <- channel (2ks+(j>>2))*16 + q*4 + (j&3).
__device__ __forceinline__ v8s relay(v4f e, v4f o) {
    v4u w;
    w[0] = pk2(leaky(e[0]), leaky(e[1]));
    w[1] = pk2(leaky(e[2]), leaky(e[3]));
    w[2] = pk2(leaky(o[0]), leaky(o[1]));
    w[3] = pk2(leaky(o[2]), leaky(o[3]));
    return __builtin_bit_cast(v8s, w);
}

// 512-thread blocks, min-waves 2 (VGPR cap 256). Register-budget ledger from
// 12 rounds: body live set ~64 -> compiler lands at exactly 64 VGPR = the
// 8-waves/SIMD granule. ANY addition beyond ~20 regs (L1 hoist +64, R11) or
// any tighter bound (R4 (512,6); R11 (512,4)) spills or starves. DO NOT TOUCH.
__global__ __launch_bounds__(512, 2)
void cmfsm_kernel(const float* __restrict__ lr, const float* __restrict__ hr,
                  const float* __restrict__ w0g, const float* __restrict__ w1g,
                  const float* __restrict__ w2g, const float* __restrict__ w3g,
                  const float* __restrict__ w4g, const float* __restrict__ w5g,
                  const float* __restrict__ t0g, const float* __restrict__ t1g,
                  const float* __restrict__ t2g, const float* __restrict__ fwg,
                  float* __restrict__ out)
{
    extern __shared__ unsigned short smem[];
    unsigned short* wfrag = smem;                    // 53*512 shorts

    const int tid  = threadIdx.x;
    const int lane = tid & 63;
    const int wv   = tid >> 6;    // 0..7
    const int p    = lane & 15;   // MFMA n (pixel)
    const int q    = lane >> 4;   // MFMA k-quad

    // ---- stage weights as A-fragments into LDS, fragment-major ----
    // layer 0: identity K mapping (B built straight from global loads)
    for (int e = tid; e < 32 * 64; e += 512) {
        int f = e >> 6, l = e & 63;
        int mt = f >> 2, ks = f & 3, pp = l & 15, qq = l >> 4;
        const float* src = w0g + (mt * 16 + pp) * 128 + ks * 32 + qq * 8;
        unsigned short* dst = wfrag + f * 512 + l * 8;
#pragma unroll
        for (int j = 0; j < 8; ++j) dst[j] = f2bf(src[j]);
    }
    // layers 1..3: K-permuted so B comes from the register relay.
    // slot (ks, qq, j) <- input channel ks*32 + ((j>>2)<<4) + qq*4 + (j&3)
    for (int e = tid; e < 16 * 64; e += 512) {
        int f = e >> 6, l = e & 63;
        int mt = f >> 2, ks = f & 3, pp = l & 15, qq = l >> 4;
        const float* srcrow = w1g + (mt * 16 + pp) * 128;
        unsigned short* dst = wfrag + (32 + f) * 512 + l * 8;
#pragma unroll
        for (int j = 0; j < 8; ++j)
            dst[j] = f2bf(srcrow[ks * 32 + ((j >> 2) << 4) + qq * 4 + (j & 3)]);
    }
    if (tid < 4 * 64) {
        int f = tid >> 6, l = tid & 63;
        int mt = f >> 1, ks = f & 1, pp = l & 15, qq = l >> 4;
        const float* srcrow = w2g + (mt * 16 + pp) * 64;
        unsigned short* dst = wfrag + (48 + f) * 512 + l * 8;
#pragma unroll
        for (int j = 0; j < 8; ++j)
            dst[j] = f2bf(srcrow[ks * 32 + ((j >> 2) << 4) + qq * 4 + (j & 3)]);
    }
    if (tid < 64) {
        int l = tid;
        int pp = l & 15, qq = l >> 4;
        const float* srcrow = w3g + pp * 32;
        unsigned short* dst = wfrag + 52 * 512 + l * 8;
#pragma unroll
        for (int j = 0; j < 8; ++j)
            dst[j] = f2bf(srcrow[((j >> 2) << 4) + qq * 4 + (j & 3)]);
    }

    // ---- fused linear layers 4+5: w45[r] = sum_j w5[j]*w4[j][4q+r] ----
    float w45[4];
#pragma unroll
    for (int r = 0; r < 4; ++r) {
        float s = 0.f;
#pragma unroll
        for (int j = 0; j < 8; ++j) s += w5g[j] * w4g[j * 16 + q * 4 + r];
        w45[r] = s;
    }

    // ---- weights2: 4 parity values; row parity is block-uniform (y = blockIdx) ----
    float w2e, w2o;   // value for even-x / odd-x pixels of this row
    {
        float tab[4];
#pragma unroll
        for (int yp = 0; yp < 2; ++yp)
#pragma unroll
            for (int xp = 0; xp < 2; ++xp) {
                float i0 = xp ? 1.f : -1.f;
                float i1 = yp ? 1.f : -1.f;
                float i2 = 1.41421356237309505f;
                float h0[3], h1[2];
                for (int o = 0; o < 3; ++o)
                    h0[o] = leaky(t0g[o*3+0]*i0 + t0g[o*3+1]*i1 + t0g[o*3+2]*i2);
                for (int o = 0; o < 2; ++o)
                    h1[o] = leaky(t1g[o*3+0]*h0[0] + t1g[o*3+1]*h0[1] + t1g[o*3+2]*h0[2]);
                tab[yp*2+xp] = t2g[0]*h1[0] + t2g[1]*h1[1];
            }
        const int yp = blockIdx.x & 1;
        w2e = yp ? tab[2] : tab[0];
        w2o = yp ? tab[3] : tab[1];
    }
    const float fa = fabsf(fwg[0]);
    const float fb = fabsf(fwg[1]);

    __syncthreads();   // wfrag ready; everything after is wave-private

    const unsigned short* WL = wfrag + lane * 8;     // A-frag read base

    // ---- per-lane per-channel global pointers: lane (q,p) owns ch = q*8+j ----
    const float* hrp[8];
    const float* lrp[8];
    {
        const int hbase = blockIdx.x * Wh + wv * 16 + p;
        const int lbase = (blockIdx.x >> 1) * Wlr + wv * 8 + (p >> 1);
#pragma unroll
        for (int j = 0; j < 8; ++j) {
            hrp[j] = hr + (size_t)(q * 8 + j) * HWh  + hbase;
            lrp[j] = lr + (size_t)(q * 8 + j) * HWlr + lbase;
        }
    }

    // ---- hoist the serial-tail A-fragments only (layers 2+3, 20 VGPR — R6 win).
    // L1 hoist (+64 VGPR) is a PROVEN dead end: spills under cap (R11) or
    // starves concurrency without (R7).
    const v8s a2w[4] = {
        *(const v8s*)(WL + 48 * 512), *(const v8s*)(WL + 49 * 512),
        *(const v8s*)(WL + 50 * 512), *(const v8s*)(WL + 51 * 512)
    };
    const v8s a3 = *(const v8s*)(WL + 52 * 512);

    // persistent zero C-tuple: chains start as mfma(a,b,z4) — removes ~56
    // v_mov zero-inits per wave-iter (isolated this round on the R6 champion)
    const v4f z4 = (v4f){0.f, 0.f, 0.f, 0.f};

    // output column base for this wave (q==0 lanes store)
    const int obase = blockIdx.x * Wh + wv * 16 + p;

    // ---- software pipeline: preload iteration 0's staging values ----
    float h[8], l[8];
#pragma unroll
    for (int j = 0; j < 8; ++j) { h[j] = hrp[j][0]; l[j] = lrp[j][0]; }

#pragma unroll
    for (int it = 0; it < ITERS; ++it) {
        // ---- layer-0 B fragments in registers ----
        //   ks0 = lr_up, ks1 = hr, ks2 = lr*hr, ks3 = (lr-hr)^2
        v4u bf0, bf1, bf2, bf3;
#pragma unroll
        for (int u = 0; u < 4; ++u) {
            float l0 = l[2*u], l1 = l[2*u+1];
            float h0 = h[2*u], h1 = h[2*u+1];
            bf0[u] = pk2(l0, l1);
            bf1[u] = pk2(h0, h1);
            bf2[u] = pk2(l0 * h0, l1 * h1);
            float d0 = l0 - h0, d1 = l1 - h1;
            bf3[u] = pk2(d0 * d0, d1 * d1);
        }
        v8s b0 = __builtin_bit_cast(v8s, bf0);
        v8s b1 = __builtin_bit_cast(v8s, bf1);
        v8s b2 = __builtin_bit_cast(v8s, bf2);
        v8s b3 = __builtin_bit_cast(v8s, bf3);

        // ---- prefetch next iteration (all-immediate addressing, it static) ----
        if (it + 1 < ITERS) {
            const int ho = (it + 1) * 128;   // hr: +128 floats/iter (imm 512B steps)
            const int lo = (it + 1) * 64;    // lr: +64 floats/iter  (imm 256B steps)
#pragma unroll
            for (int j = 0; j < 8; ++j) {
                h[j] = hrp[j][ho];
                l[j] = lrp[j][lo];
            }
        }

        // ---- layer 0: 128 -> 128, pair-wise relay, zero-peeled chains ----
        v8s c1[4];
#pragma unroll
        for (int ksp = 0; ksp < 4; ++ksp) {
            v4f ae = __builtin_amdgcn_mfma_f32_16x16x32_bf16(
                         *(const v8s*)(WL + ((2 * ksp)     * 4) * 512), b0, z4, 0, 0, 0);
            v4f ao = __builtin_amdgcn_mfma_f32_16x16x32_bf16(
                         *(const v8s*)(WL + ((2 * ksp + 1) * 4) * 512), b0, z4, 0, 0, 0);
#pragma unroll
            for (int ks = 1; ks < 4; ++ks) {
                v8s b = (ks == 1) ? b1 : (ks == 2) ? b2 : b3;
                v8s we = *(const v8s*)(WL + ((2 * ksp)     * 4 + ks) * 512);
                v8s wo = *(const v8s*)(WL + ((2 * ksp + 1) * 4 + ks) * 512);
                ae = __builtin_amdgcn_mfma_f32_16x16x32_bf16(we, b, ae, 0, 0, 0);
                ao = __builtin_amdgcn_mfma_f32_16x16x32_bf16(wo, b, ao, 0, 0, 0);
            }
            c1[ksp] = relay(ae, ao);
        }

        // ---- layer 1: 128 -> 64, pair-wise, zero-peeled (A-frags from LDS) ----
        v8s c2[2];
#pragma unroll
        for (int ksp = 0; ksp < 2; ++ksp) {
            v4f ae = __builtin_amdgcn_mfma_f32_16x16x32_bf16(
                         *(const v8s*)(WL + (32 + (2 * ksp)     * 4) * 512), c1[0], z4, 0, 0, 0);
            v4f ao = __builtin_amdgcn_mfma_f32_16x16x32_bf16(
                         *(const v8s*)(WL + (32 + (2 * ksp + 1) * 4) * 512), c1[0], z4, 0, 0, 0);
#pragma unroll
            for (int ks = 1; ks < 4; ++ks) {
                v8s we = *(const v8s*)(WL + (32 + (2 * ksp)     * 4 + ks) * 512);
                v8s wo = *(const v8s*)(WL + (32 + (2 * ksp + 1) * 4 + ks) * 512);
                ae = __builtin_amdgcn_mfma_f32_16x16x32_bf16(we, c1[ks], ae, 0, 0, 0);
                ao = __builtin_amdgcn_mfma_f32_16x16x32_bf16(wo, c1[ks], ao, 0, 0, 0);
            }
            c2[ksp] = relay(ae, ao);
        }

        // ---- layer 2: 64 -> 32 (single pair, A-frags in registers, zero-peeled) ----
        v8s c3;
        {
            v4f ae = __builtin_amdgcn_mfma_f32_16x16x32_bf16(a2w[0], c2[0], z4, 0, 0, 0);
            v4f ao = __builtin_amdgcn_mfma_f32_16x16x32_bf16(a2w[2], c2[0], z4, 0, 0, 0);
            ae = __builtin_amdgcn_mfma_f32_16x16x32_bf16(a2w[1], c2[1], ae, 0, 0, 0);
            ao = __builtin_amdgcn_mfma_f32_16x16x32_bf16(a2w[3], c2[1], ao, 0, 0, 0);
            c3 = relay(ae, ao);
        }

        // ---- layer 3: 32 -> 16, fused 16->8->1, fuse with weights2 ----
        {
            v4f acc3 = __builtin_amdgcn_mfma_f32_16x16x32_bf16(a3, c3, z4, 0, 0, 0);

            float part = 0.f;
#pragma unroll
            for (int r = 0; r < 4; ++r) part += w45[r] * leaky(acc3[r]);
            part += __shfl_xor(part, 16, 64);
            part += __shfl_xor(part, 32, 64);

            if (q == 0) {
                const float w2v = (p & 1) ? w2o : w2e;
                out[obase + it * 128] = fa * part + fb * w2v;
            }
        }
    }
}

extern "C" void kernel_launch(void* const* d_in, const int* in_sizes, int n_in,
                              void* d_out, int out_size, void* d_ws, size_t ws_size,
                              hipStream_t stream) {
    const float* lr  = (const float*)d_in[0];
    const float* hr  = (const float*)d_in[1];
    const float* w0g = (const float*)d_in[2];
    const float* w1g = (const float*)d_in[3];
    const float* w2g = (const float*)d_in[4];
    const float* w3g = (const float*)d_in[5];
    const float* w4g = (const float*)d_in[6];
    const float* w5g = (const float*)d_in[7];
    const float* t0g = (const float*)d_in[8];
    const float* t1g = (const float*)d_in[9];
    const float* t2g = (const float*)d_in[10];
    const float* fwg = (const float*)d_in[11];
    float* out = (float*)d_out;

    hipLaunchKernelGGL(cmfsm_kernel, dim3(NBLK), dim3(512), LDS_BYTES, stream,
                       lr, hr, w0g, w1g, w2g, w3g, w4g, w5g, t0g, t1g, t2g, fwg, out);
}